// Round 2
// baseline (10967.358 us; speedup 1.0000x reference)
//
#include <hip/hip_runtime.h>
#include <math.h>

#define BB 2048
#define TT 512
#define NFEAT 25
#define UNITS 300
#define NZ 1200
#define KPAD 352        // 325 padded to 11*32
#define NKS 11          // K-steps of 32
#define NTILES 75       // 1200 / 16
#define RPB 8           // rows per block
#define NT 512          // threads per block

typedef __attribute__((ext_vector_type(4))) float f32x4;
typedef __attribute__((ext_vector_type(8))) short bf16x8;

static __device__ __forceinline__ unsigned short f2bf(float f) {
    union { float f; unsigned u; } x; x.f = f;
    unsigned r = (x.u + 0x7fffu + ((x.u >> 16) & 1u)) >> 16;
    return (unsigned short)r;
}

// Pre-kernel: fp32 [wk;wr] -> bf16 in MFMA B-fragment order.
// flat idx = (nt*NKS + ks)*512 + kg*128 + n*8 + j
//   maps to  B[k = ks*32 + kg*8 + j][col = nt*16 + n]
__global__ __launch_bounds__(256) void conv_weights(
    const float* __restrict__ wk, const float* __restrict__ wr,
    unsigned short* __restrict__ wsB)
{
    int idx = blockIdx.x * 256 + threadIdx.x;
    if (idx >= NTILES * NKS * 512) return;
    int j  = idx & 7;
    int n  = (idx >> 3) & 15;
    int kg = (idx >> 7) & 3;
    int q  = idx >> 9;            // nt*NKS + ks
    int ks = q % NKS;
    int nt = q / NKS;
    int k   = ks * 32 + kg * 8 + j;
    int col = nt * 16 + n;
    float v = 0.f;
    if (k < 25)       v = wk[k * NZ + col];
    else if (k < 325) v = wr[(k - 25) * NZ + col];
    wsB[idx] = f2bf(v);
}

__global__ __launch_bounds__(NT) void dilstm_persist(
    const float* __restrict__ x,    // [B][T][25]
    const unsigned short* __restrict__ wsB, // bf16 fragments, 75*11*512
    const float* __restrict__ bz,   // [1200]
    const float* __restrict__ w1,   // [50][50]
    const float* __restrict__ b1,   // [50]
    const float* __restrict__ w2,   // [50][24]
    const float* __restrict__ b2,   // [24]
    const float* __restrict__ wa,   // [300][8]
    const float* __restrict__ ba,   // [8]
    const float* __restrict__ wm,
    const float* __restrict__ bm,
    const float* __restrict__ wsg,
    const float* __restrict__ bs,
    float* __restrict__ out)        // [B][T][25]
{
    __shared__ unsigned short Abf[16][KPAD]; // bf16 A: [0..24]=gate_out, [25..324]=h; rows 8..15 & k>=325 stay 0
    __shared__ float Hf[RPB][UNITS];         // fp32 h for heads
    __shared__ float Cc[RPB][UNITS];         // cell state
    __shared__ float Zb[RPB][NZ];            // z staging
    __shared__ float XT[RPB][NFEAT];
    __shared__ float Prev[RPB][NFEAT];
    __shared__ float Gin[RPB][50];
    __shared__ float G1[RPB][50];
    __shared__ float Sc[RPB][24];
    __shared__ float Comb[RPB];

    const int t = threadIdx.x;
    const int row0 = blockIdx.x * RPB;

    // zero-init persistent state
    for (int i = t; i < 16 * KPAD; i += NT) ((unsigned short*)Abf)[i] = 0;
    for (int i = t; i < RPB * UNITS; i += NT) { ((float*)Cc)[i] = 0.f; ((float*)Hf)[i] = 0.f; }
    for (int i = t; i < RPB * NFEAT; i += NT) ((float*)Prev)[i] = 0.f;
    __syncthreads();

    const int rA = t / 25, eA = t % 25;   // 200-thread phases
    const int rM = t >> 6, uM = t & 63;   // 8 x 64 phases
    const int lane = t & 63;
    const int wv = t >> 6;
    const int arow = lane & 15;           // A-fragment row
    const int akg  = lane >> 4;           // A-fragment k-group (0..3)

    for (int ts = 0; ts < TT; ++ts) {
        // ---- A1: load x_t, combined ----
        if (t < 200) {
            float xv = x[((size_t)(row0 + rA) * TT + ts) * NFEAT + eA];
            XT[rA][eA] = xv;
            if (eA == 24) Comb[rA] = xv + Prev[rA][24];
        }
        __syncthreads();
        // ---- A2: gate-MLP input ----
        if (t < 200) {
            if (eA < 24) {
                Gin[rA][eA]      = XT[rA][eA];
                Gin[rA][25 + eA] = Prev[rA][eA];
            } else {
                float denom = fmaxf(Comb[rA], 1e-8f);
                Gin[rA][24] = XT[rA][24]   / denom;
                Gin[rA][49] = Prev[rA][24] / denom;
            }
        }
        __syncthreads();
        // ---- MLP layer 1 ----
        if (uM < 50) {
            float a = b1[uM];
            #pragma unroll
            for (int k = 0; k < 50; ++k) a += Gin[rM][k] * w1[k * 50 + uM];
            G1[rM][uM] = fmaxf(a, 0.f);
        }
        __syncthreads();
        // ---- MLP layer 2 -> Abf[.][0..24] ----
        if (uM < 24) {
            float a = b2[uM];
            #pragma unroll
            for (int k = 0; k < 50; ++k) a += G1[rM][k] * w2[k * 24 + uM];
            Abf[rM][uM] = f2bf(a);
        } else if (uM == 24) {
            Abf[rM][24] = f2bf(Comb[rM]);
        }
        __syncthreads();
        // ---- big GEMM via MFMA: z[16pad x 1200] = Abf @ B ----
        {
            bf16x8 afrag[NKS];
            #pragma unroll
            for (int ks = 0; ks < NKS; ++ks)
                afrag[ks] = *(const bf16x8*)&Abf[arow][ks * 32 + akg * 8];

            const int nn = lane & 15;
            for (int nt = wv; nt < NTILES; nt += 8) {
                const unsigned short* bp = wsB + (size_t)(nt * NKS) * 512 + ((akg * 16 + nn) << 3);
                f32x4 acc = {0.f, 0.f, 0.f, 0.f};
                #pragma unroll
                for (int ks = 0; ks < NKS; ++ks) {
                    bf16x8 b = *(const bf16x8*)(bp + ks * 512);
                    acc = __builtin_amdgcn_mfma_f32_16x16x32_bf16(afrag[ks], b, acc, 0, 0, 0);
                }
                if (lane < 32) {
                    int col = nt * 16 + nn;
                    int r0 = (lane >> 4) * 4;
                    float bc = bz[col];
                    #pragma unroll
                    for (int rg = 0; rg < 4; ++rg)
                        Zb[r0 + rg][col] = acc[rg] + bc;
                }
            }
        }
        __syncthreads();
        // ---- LSTM cell ----
        if (t < UNITS) {
            #pragma unroll
            for (int r = 0; r < RPB; ++r) {
                float zi = Zb[r][t], zf = Zb[r][t + 300];
                float zc = Zb[r][t + 600], zo = Zb[r][t + 900];
                float ig = fminf(fmaxf(0.2f * zi + 0.5f, 0.f), 1.f);
                float fg = fminf(fmaxf(0.2f * zf + 0.5f, 0.f), 1.f);
                float og = fminf(fmaxf(0.2f * zo + 0.5f, 0.f), 1.f);
                float cn = fg * Cc[r][t] + ig * tanhf(zc);
                Cc[r][t] = cn;
                float hn = og * tanhf(cn);
                Hf[r][t] = hn;
                Abf[r][25 + t] = f2bf(hn);
            }
        }
        __syncthreads();
        // ---- MDN heads ----
        if (uM < 24) {
            int head = uM >> 3, mix = uM & 7;
            const float* W  = (head == 0) ? wa : (head == 1) ? wm : wsg;
            const float* Bv = (head == 0) ? ba : (head == 1) ? bm : bs;
            float a = Bv[mix];
            for (int u = 0; u < UNITS; ++u) a += Hf[rM][u] * W[u * 8 + mix];
            Sc[rM][uM] = a;
        }
        __syncthreads();
        // ---- softmax / nnelu + output ----
        if (t < 200) {
            float v;
            if (eA < 8) {
                float mx = Sc[rA][0];
                #pragma unroll
                for (int m = 1; m < 8; ++m) mx = fmaxf(mx, Sc[rA][m]);
                float sum = 0.f;
                #pragma unroll
                for (int m = 0; m < 8; ++m) sum += expf(Sc[rA][m] - mx);
                v = expf(Sc[rA][eA] - mx) / sum;
            } else if (eA < 16) {
                v = Sc[rA][eA];
            } else if (eA < 24) {
                float s = Sc[rA][eA];
                v = (s > 0.f) ? (1.f + s) : expf(s);
            } else {
                v = Comb[rA];
            }
            Prev[rA][eA] = v;
            out[((size_t)(row0 + rA) * TT + ts) * NFEAT + eA] = v;
        }
        __syncthreads();
    }
}

extern "C" void kernel_launch(void* const* d_in, const int* in_sizes, int n_in,
                              void* d_out, int out_size, void* d_ws, size_t ws_size,
                              hipStream_t stream) {
    const float* x   = (const float*)d_in[0];
    const float* wk  = (const float*)d_in[1];
    const float* wr  = (const float*)d_in[2];
    const float* bz  = (const float*)d_in[3];
    const float* w1  = (const float*)d_in[4];
    const float* b1  = (const float*)d_in[5];
    const float* w2  = (const float*)d_in[6];
    const float* b2  = (const float*)d_in[7];
    const float* wa  = (const float*)d_in[8];
    const float* ba  = (const float*)d_in[9];
    const float* wm  = (const float*)d_in[10];
    const float* bm  = (const float*)d_in[11];
    const float* wsg = (const float*)d_in[12];
    const float* bs  = (const float*)d_in[13];
    float* out = (float*)d_out;
    unsigned short* wsB = (unsigned short*)d_ws;

    const int nconv = NTILES * NKS * 512;
    conv_weights<<<(nconv + 255) / 256, 256, 0, stream>>>(wk, wr, wsB);
    dilstm_persist<<<BB / RPB, NT, 0, stream>>>(
        x, wsB, bz, w1, b1, w2, b2, wa, ba, wm, bm, wsg, bs, out);
}